// Round 8
// baseline (1565.928 us; speedup 1.0000x reference)
//
#include <hip/hip_runtime.h>
#include <cstdint>
#include <cstddef>

// ConvGRU autoencoder, round 8: explicit weight placement + 2-co-group retile.
// vs r7: (a) e1/d0 retiled 2 co-groups x 4 f-groups (wave owns 2 cot x 2 ft)
// -> activation-fragment read redundancy halved for the big layers;
// (b) big gate sets explicitly LDS-resident (enc: e1g@0 + e0g@73728; dec:
// d0g@0) -- kills the phantom per-t global weight reloads (VGPR=120 showed the
// compiler was NOT keeping the old "register" weights);
// (c) small sets truly in regs (e0c, e1c, d1 gates), d0c/d1c streamed from
// L1/L2 per t on the vector-memory pipe (parallel to LDS), hidden under convB.
//
// aT (28 cb x 130 rows x 8 f16) @ byte 100352 -- layout identical to r7:
//  enc: cb0 x, cb1-4 h0, cb5-12 h1, cb13 x-dup, cb14-17 rh0, cb18-25 rh1
//  dec: cb0-7 y1, cb8-15 hd0, cb16-19 hd1, cb20-27 rh

#define F_ 128
#define T_ 100
#define B_ 64
#define ROWSP 130
#define CBSTR (ROWSP * 8)    // f16 per cb
#define CBBYTE (ROWSP * 16)  // bytes per cb
#define AT_OFF 100352
#define LDS_TOTAL (AT_OFF + 28 * CBBYTE)  // 100352 + 58240 = 158592

typedef _Float16 f16;
typedef __attribute__((ext_vector_type(4))) float f32x4;
typedef __attribute__((ext_vector_type(8))) _Float16 f16x8;
typedef __attribute__((ext_vector_type(4))) _Float16 f16x4;

#define MFMA(a, b, c) __builtin_amdgcn_mfma_f32_16x16x32_f16(a, b, c, 0, 0, 0)

__device__ __forceinline__ float exp2_(float x) { return __builtin_amdgcn_exp2f(x); }
__device__ __forceinline__ float rcp_(float x) { return __builtin_amdgcn_rcpf(x); }

#define KSG (-1.442695041f)  // sigmoid: sig(v) = rcp(1+exp2(v*KSG))
#define KTH (-2.885390082f)  // tanh:    tanh(v) = 2*rcp(1+exp2(v*KTH)) - 1

// cb base per (layer, ks%NC3); fragment cb = base + kb (kb = lane>>4).
__host__ __device__ constexpr int cbA(int lid, int km) {
  return lid == 0 ? (km ? 4 : 0)
       : lid == 1 ? (1 + km * 4)
       : lid == 2 ? (km * 4)
                  : (8 + km * 4);
}
__host__ __device__ constexpr int cbB(int lid, int km) {
  return lid == 0 ? (km ? 17 : 13)
       : lid == 1 ? (km == 0 ? 1 : 14 + km * 4)
       : lid == 2 ? (km < 2 ? km * 4 : 12 + km * 4)
                  : (km < 2 ? 8 + km * 4 : 20);
}

// One GRU layer step. Wave owns COT cot-tiles x 2 f-tiles. Gate weights from
// LDS (gR/gU per-thread bases) or regs (aRr/aUr); cand from regs (cRr) or
// streamed global (cGb). One internal barrier (after rh write). Caller
// barriers before (inputs ready) and after (h visible).
template <int LID, int COT, int NK, int NC3, int HCB, int RHCB,
          bool GREG, bool CGLOB, bool EMITY1>
__device__ __forceinline__ void gru_layer(
    const f16* __restrict__ rdB, char* __restrict__ wrB,
    const f16* __restrict__ gR, const f16* __restrict__ gU,
    const f16x8* __restrict__ aRr, const f16x8* __restrict__ aUr,
    const f16x8* __restrict__ cRr, const f16* __restrict__ cGb,
    const f32x4 bR0, const f32x4 bR1, const f32x4 bU0, const f32x4 bU1,
    const f32x4 bC0, const f32x4 bC1,
    f32x4* __restrict__ hreg, f16* __restrict__ y1dst) {
  // ---- conv A: R,U gates over [x ; h] ----
  f32x4 accR[COT][2], accU[COT][2];
#pragma unroll
  for (int i = 0; i < COT; ++i)
#pragma unroll
    for (int j = 0; j < 2; ++j) {
      accR[i][j] = (f32x4){0.f, 0.f, 0.f, 0.f};
      accU[i][j] = (f32x4){0.f, 0.f, 0.f, 0.f};
    }
#pragma unroll
  for (int ks = 0; ks < NK; ++ks) {
    const int k = ks / NC3, km = ks % NC3;
    const f16* fb = rdB + cbA(LID, km) * CBSTR + k * 8;
    const f16x8 b0 = *(const f16x8*)(fb);
    const f16x8 b1 = *(const f16x8*)(fb + 128);
#pragma unroll
    for (int i = 0; i < COT; ++i) {
      f16x8 wr, wu;
      if constexpr (GREG) {
        wr = aRr[i * NK + ks];
        wu = aUr[i * NK + ks];
      } else {
        wr = *(const f16x8*)(gR + (i * NK + ks) * 512);
        wu = *(const f16x8*)(gU + (i * NK + ks) * 512);
      }
      accR[i][0] = MFMA(wr, b0, accR[i][0]);
      accR[i][1] = MFMA(wr, b1, accR[i][1]);
      accU[i][0] = MFMA(wu, b0, accU[i][0]);
      accU[i][1] = MFMA(wu, b1, accU[i][1]);
    }
  }
  // ---- post A: u = sigm(U) in regs; rh = sigm(R)*h into rh cols ----
  f32x4 u[COT][2];
#pragma unroll
  for (int i = 0; i < COT; ++i) {
    const f32x4 bR = i ? bR1 : bR0;
    const f32x4 bU = i ? bU1 : bU0;
#pragma unroll
    for (int j = 0; j < 2; ++j) {
      f16x4 rh;
#pragma unroll
      for (int q = 0; q < 4; ++q) {
        u[i][j][q] = rcp_(1.0f + exp2_(fmaf(accU[i][j][q], KSG, bU[q])));
        const float r = rcp_(1.0f + exp2_(fmaf(accR[i][j][q], KSG, bR[q])));
        rh[q] = (f16)(r * hreg[i * 2 + j][q]);
      }
      *(f16x4*)(wrB + (RHCB - HCB) * CBBYTE + i * 2 * CBBYTE + j * 256) = rh;
    }
  }
  __syncthreads();  // rh visible
  // ---- conv B: candidate over [x ; r*h] ----
  f32x4 accC[COT][2];
#pragma unroll
  for (int i = 0; i < COT; ++i)
#pragma unroll
    for (int j = 0; j < 2; ++j) accC[i][j] = (f32x4){0.f, 0.f, 0.f, 0.f};
#pragma unroll
  for (int ks = 0; ks < NK; ++ks) {
    const int k = ks / NC3, km = ks % NC3;
    const f16* fb = rdB + cbB(LID, km) * CBSTR + k * 8;
    const f16x8 b0 = *(const f16x8*)(fb);
    const f16x8 b1 = *(const f16x8*)(fb + 128);
#pragma unroll
    for (int i = 0; i < COT; ++i) {
      f16x8 wc;
      if constexpr (CGLOB) wc = *(const f16x8*)(cGb + (i * NK + ks) * 512);
      else wc = cRr[i * NK + ks];
      accC[i][0] = MFMA(wc, b0, accC[i][0]);
      accC[i][1] = MFMA(wc, b1, accC[i][1]);
    }
  }
  // ---- post B: h = h + u*(tanh(C)-h); write h cols; optional y1 emit ----
#pragma unroll
  for (int i = 0; i < COT; ++i) {
    const f32x4 bC = i ? bC1 : bC0;
#pragma unroll
    for (int j = 0; j < 2; ++j) {
      f16x4 hh;
#pragma unroll
      for (int q = 0; q < 4; ++q) {
        const float r = rcp_(1.0f + exp2_(fmaf(accC[i][j][q], KTH, bC[q])));
        const float h = hreg[i * 2 + j][q];
        const float s = fmaf(2.0f, r, -(1.0f + h));  // tanh(C) - h
        const float hn = fmaf(u[i][j][q], s, h);
        hreg[i * 2 + j][q] = hn;
        hh[q] = (f16)hn;
      }
      *(f16x4*)(wrB + i * 2 * CBBYTE + j * 256) = hh;
      if constexpr (EMITY1) *(f16x4*)(y1dst + i * 2048 + j * 128) = hh;
    }
  }
}

__global__ __launch_bounds__(512, 2) void ae_kernel(
    const f16* __restrict__ xf, float* __restrict__ out,
    const f16* __restrict__ wgE0, const f16* __restrict__ wcE0,
    const float* __restrict__ bgE0, const float* __restrict__ bcE0,
    const f16* __restrict__ wgE1, const f16* __restrict__ wcE1,
    const float* __restrict__ bgE1, const float* __restrict__ bcE1,
    const f16* __restrict__ wgD0, const f16* __restrict__ wcD0,
    const float* __restrict__ bgD0, const float* __restrict__ bcD0,
    const f16* __restrict__ wgD1, const f16* __restrict__ wcD1,
    const float* __restrict__ bgD1, const float* __restrict__ bcD1,
    const float* __restrict__ fw, const float* __restrict__ fb,
    f16* __restrict__ y1g) {
  extern __shared__ char smem[];
  f16* aT = (f16*)(smem + AT_OFF);
  char* atB = smem + AT_OFF;
  const int tid = threadIdx.x, b = blockIdx.x;
  const int w = tid >> 6, l = tid & 63;
  const int m16 = l & 15, kb = l >> 4, kb4 = kb * 4;
  const int cg = w & 1, fg = w >> 1;

  // zero aT (28 cb)
  for (int i = tid; i < 28 * CBBYTE / 16; i += 512)
    ((f32x4*)atB)[i] = (f32x4){0.f, 0.f, 0.f, 0.f};
  // enc weights -> LDS: e1g (73728 B) @0, e0g (24576 B) @73728
  for (int i = tid; i < 4608; i += 512)
    ((f16x8*)smem)[i] = ((const f16x8*)wgE1)[i];
  for (int i = tid; i < 1536; i += 512)
    ((f16x8*)(smem + 73728))[i] = ((const f16x8*)wgE0)[i];

  // small candidate sets -> regs
  f16x8 cE0[6], cE1[18];
#pragma unroll
  for (int ks = 0; ks < 6; ++ks)
    cE0[ks] = ((const f16x8*)wcE0)[(cg * 6 + ks) * 64 + l];
#pragma unroll
  for (int i = 0; i < 2; ++i)
#pragma unroll
    for (int ks = 0; ks < 9; ++ks)
      cE1[i * 9 + ks] = ((const f16x8*)wcE1)[((2 * cg + i) * 9 + ks) * 64 + l];

  // enc biases (scale folded)
  const int co2 = cg * 16 + kb4;
  const int coA = (2 * cg) * 16 + kb4, coB = (2 * cg + 1) * 16 + kb4;
  f32x4 bRe0, bUe0, bCe0, bRe1a, bRe1b, bUe1a, bUe1b, bCe1a, bCe1b;
#pragma unroll
  for (int q = 0; q < 4; ++q) {
    bRe0[q] = bgE0[co2 + q] * KSG;
    bUe0[q] = bgE0[32 + co2 + q] * KSG;
    bCe0[q] = bcE0[co2 + q] * KTH;
    bRe1a[q] = bgE1[coA + q] * KSG;
    bRe1b[q] = bgE1[coB + q] * KSG;
    bUe1a[q] = bgE1[64 + coA + q] * KSG;
    bUe1b[q] = bgE1[64 + coB + q] * KSG;
    bCe1a[q] = bcE1[coA + q] * KTH;
    bCe1b[q] = bcE1[coB + q] * KTH;
  }

  // per-thread bases
  const f16* rdB = aT + kb * CBSTR + (fg * 32 + m16) * 8;
  const int rowb = (fg * 32 + m16 + 1) * 16 + (kb & 1) * 8;
  char* wrE0 = atB + (1 + cg * 2 + (kb >> 1)) * CBBYTE + rowb;
  char* wrE1 = atB + (5 + 4 * cg + (kb >> 1)) * CBBYTE + rowb;
  char* wrD0 = atB + (8 + 4 * cg + (kb >> 1)) * CBBYTE + rowb;
  char* wrD1 = atB + (16 + cg * 2 + (kb >> 1)) * CBBYTE + rowb;
  const f16* gRe1 = (const f16*)smem + (2 * cg * 9) * 512 + l * 8;
  const f16* gUe1 = (const f16*)smem + ((4 + 2 * cg) * 9) * 512 + l * 8;
  const f16* gRe0 = (const f16*)(smem + 73728) + (cg * 6) * 512 + l * 8;
  const f16* gUe0 = (const f16*)(smem + 73728) + ((2 + cg) * 6) * 512 + l * 8;
  f16* y1t = y1g + (size_t)b * T_ * 8192 +
             ((4 * cg + (kb >> 1)) * 128 + fg * 32 + m16) * 8 + (kb & 1) * 4;

  f32x4 h0r[2], h1r[4];
#pragma unroll
  for (int j = 0; j < 2; ++j) h0r[j] = (f32x4){0.f, 0.f, 0.f, 0.f};
#pragma unroll
  for (int j = 0; j < 4; ++j) h1r[j] = (f32x4){0.f, 0.f, 0.f, 0.f};
  __syncthreads();

  // ================= encoder =================
  const f16* xb = xf + (size_t)b * T_ * F_;
  for (int t = 0; t < T_; ++t) {
    if (tid < F_) {  // x into col 0 (cb0) and dup col 104 (cb13)
      const f16 v = xb[t * F_ + tid];
      aT[(tid + 1) * 8] = v;
      aT[13 * CBSTR + (tid + 1) * 8] = v;
    }
    __syncthreads();
    gru_layer<0, 1, 6, 2, 1, 14, false, false, false>(
        rdB, wrE0, gRe0, gUe0, nullptr, nullptr, cE0, nullptr,
        bRe0, bRe0, bUe0, bUe0, bCe0, bCe0, h0r, nullptr);
    __syncthreads();
    gru_layer<1, 2, 9, 3, 5, 18, false, false, true>(
        rdB, wrE1, gRe1, gUe1, nullptr, nullptr, cE1, nullptr,
        bRe1a, bRe1b, bUe1a, bUe1b, bCe1a, bCe1b, h1r, y1t + t * 8192);
    __syncthreads();
  }

  // ================= switch to decoder =================
  {  // hd0 init = h1 final (same tiling); hd1 init = h0 final
#pragma unroll
    for (int i = 0; i < 2; ++i)
#pragma unroll
      for (int j = 0; j < 2; ++j) {
        f16x4 hh;
#pragma unroll
        for (int q = 0; q < 4; ++q) hh[q] = (f16)h1r[i * 2 + j][q];
        *(f16x4*)(wrD0 + i * 2 * CBBYTE + j * 256) = hh;
      }
#pragma unroll
    for (int j = 0; j < 2; ++j) {
      f16x4 hh;
#pragma unroll
      for (int q = 0; q < 4; ++q) hh[q] = (f16)h0r[j][q];
      *(f16x4*)(wrD1 + j * 256) = hh;
    }
  }
  // d0g -> LDS @0 (overwrites enc gates; enc reads done at loop-end barrier)
  for (int i = tid; i < 6144; i += 512)
    ((f16x8*)smem)[i] = ((const f16x8*)wgD0)[i];
  // d1 gates -> regs
  f16x8 aRd1[9], aUd1[9];
#pragma unroll
  for (int ks = 0; ks < 9; ++ks) {
    aRd1[ks] = ((const f16x8*)wgD1)[(cg * 9 + ks) * 64 + l];
    aUd1[ks] = ((const f16x8*)wgD1)[((2 + cg) * 9 + ks) * 64 + l];
  }
  // dec biases
  f32x4 bRd0a, bRd0b, bUd0a, bUd0b, bCd0a, bCd0b, bRd1, bUd1, bCd1;
#pragma unroll
  for (int q = 0; q < 4; ++q) {
    bRd0a[q] = bgD0[coA + q] * KSG;
    bRd0b[q] = bgD0[coB + q] * KSG;
    bUd0a[q] = bgD0[64 + coA + q] * KSG;
    bUd0b[q] = bgD0[64 + coB + q] * KSG;
    bCd0a[q] = bcD0[coA + q] * KTH;
    bCd0b[q] = bcD0[coB + q] * KTH;
    bRd1[q] = bgD1[co2 + q] * KSG;
    bUd1[q] = bgD1[32 + co2 + q] * KSG;
    bCd1[q] = bcD1[co2 + q] * KTH;
  }
  const f16* gRd0 = (const f16*)smem + (2 * cg * 12) * 512 + l * 8;
  const f16* gUd0 = (const f16*)smem + ((4 + 2 * cg) * 12) * 512 + l * 8;
  const f16* cGd0 = (const f16*)wcD0 + (2 * cg * 12) * 512 + l * 8;
  const f16* cGd1 = (const f16*)wcD1 + (cg * 9) * 512 + l * 8;
  __syncthreads();

  // ================= decoder =================
  for (int t = 0; t < T_; ++t) {
    {  // ingest y1(t) -> cb0-7
      const f16x8* src = (const f16x8*)(y1g + ((size_t)b * T_ + t) * 8192);
#pragma unroll
      for (int k2 = 0; k2 < 2; ++k2) {
        const int i = tid + k2 * 512;
        *(f16x8*)&aT[(i >> 7) * CBSTR + ((i & 127) + 1) * 8] = src[i];
      }
    }
    __syncthreads();
    gru_layer<2, 2, 12, 4, 8, 20, false, true, false>(
        rdB, wrD0, gRd0, gUd0, nullptr, nullptr, nullptr, cGd0,
        bRd0a, bRd0b, bUd0a, bUd0b, bCd0a, bCd0b, h1r, nullptr);
    __syncthreads();
    gru_layer<3, 1, 9, 3, 16, 20, true, true, false>(
        rdB, wrD1, nullptr, nullptr, aRd1, aUd1, nullptr, cGd1,
        bRd1, bRd1, bUd1, bUd1, bCd1, bCd1, h0r, nullptr);
    __syncthreads();
    if (tid < F_) {  // final 1x1 conv over hd1 (cb16-19)
      float s = fb[0];
#pragma unroll
      for (int cb = 0; cb < 4; ++cb) {
        const f16x8 h8 = *(const f16x8*)&aT[(16 + cb) * CBSTR + (tid + 1) * 8];
#pragma unroll
        for (int q = 0; q < 8; ++q) s = fmaf(fw[cb * 8 + q], (float)h8[q], s);
      }
      out[((size_t)b * T_ + t) * F_ + tid] = s;
    }
  }
}

// (CO,CI,3,3) fp32 -> f16 packed per MFMA A-fragment (same as r7):
// dst[((cot*NK+ks)*64+lane)*8+j] = W[cot*16+(lane&15)][kk=ks*32+(lane>>4)*8+j]
__global__ void repack_f16(const float* __restrict__ src, f16* __restrict__ dst,
                           int CO, int CI, int CINH, int NK, int e0map) {
  const int n = (CO / 16) * NK * 64;
  for (int i = blockIdx.x * blockDim.x + threadIdx.x; i < n;
       i += gridDim.x * blockDim.x) {
    const int cot = i / (NK * 64);
    const int r = i - cot * NK * 64;
    const int ks = r >> 6, lph = r & 63;
    const int co = cot * 16 + (lph & 15);
    const int kbl = lph >> 4;
#pragma unroll
    for (int j = 0; j < 8; ++j) {
      const int kk = ks * 32 + kbl * 8 + j;
      const int k = kk / CINH, c = kk - k * CINH;
      int ci;
      if (e0map) ci = (c == 0) ? 0 : ((c >= 8 && c < 40) ? c - 7 : -1);
      else ci = (c < CI) ? c : -1;
      float wv = 0.f;
      if (ci >= 0) wv = src[((size_t)(co * CI + ci) * 3 + k) * 3 + 1];
      dst[(size_t)i * 8 + j] = (f16)wv;
    }
  }
}

__global__ void xcvt(const float* __restrict__ x, f16* __restrict__ xf, int n4) {
  for (int i = blockIdx.x * blockDim.x + threadIdx.x; i < n4;
       i += gridDim.x * blockDim.x) {
    const float4 v = ((const float4*)x)[i];
    f16x4 o;
    o[0] = (f16)v.x; o[1] = (f16)v.y; o[2] = (f16)v.z; o[3] = (f16)v.w;
    ((f16x4*)xf)[i] = o;
  }
}

extern "C" void kernel_launch(void* const* d_in, const int* in_sizes, int n_in,
                              void* d_out, int out_size, void* d_ws, size_t ws_size,
                              hipStream_t stream) {
  (void)in_sizes; (void)n_in; (void)out_size; (void)ws_size;
  const float* x = (const float*)d_in[0];
  const float* e0_wg = (const float*)d_in[1];
  const float* e0_bg = (const float*)d_in[2];
  const float* e0_wc = (const float*)d_in[3];
  const float* e0_bc = (const float*)d_in[4];
  const float* e1_wg = (const float*)d_in[5];
  const float* e1_bg = (const float*)d_in[6];
  const float* e1_wc = (const float*)d_in[7];
  const float* e1_bc = (const float*)d_in[8];
  const float* d0_wg = (const float*)d_in[9];
  const float* d0_bg = (const float*)d_in[10];
  const float* d0_wc = (const float*)d_in[11];
  const float* d0_bc = (const float*)d_in[12];
  const float* d1_wg = (const float*)d_in[13];
  const float* d1_bg = (const float*)d_in[14];
  const float* d1_wc = (const float*)d_in[15];
  const float* d1_bc = (const float*)d_in[16];
  const float* fw = (const float*)d_in[17];
  const float* fb = (const float*)d_in[18];
  float* out = (float*)d_out;

  char* p = (char*)d_ws;
  f16* y1g = (f16*)p;
  p += (size_t)B_ * T_ * 64 * 128 * 2;  // 104.86 MB
  f16* xf = (f16*)p;
  p += (size_t)B_ * T_ * F_ * 2;        // 1.64 MB
  auto aw = [&](int n) { f16* q = (f16*)p; p += (size_t)n * 2; return q; };
  f16* wgE0 = aw(64 * 192);
  f16* wcE0 = aw(32 * 192);
  f16* wgE1 = aw(128 * 288);
  f16* wcE1 = aw(64 * 288);
  f16* wgD0 = aw(128 * 384);
  f16* wcD0 = aw(64 * 384);
  f16* wgD1 = aw(64 * 288);
  f16* wcD1 = aw(32 * 288);

  auto rp = [&](const float* s, f16* d, int CO, int CI, int CINH, int e0m) {
    const int NK = 3 * CINH / 32;
    const int n = (CO / 16) * NK * 64;
    hipLaunchKernelGGL(repack_f16, dim3((n + 255) / 256), dim3(256), 0, stream,
                       s, d, CO, CI, CINH, NK, e0m);
  };
  rp(e0_wg, wgE0, 64, 33, 64, 1);
  rp(e0_wc, wcE0, 32, 33, 64, 1);
  rp(e1_wg, wgE1, 128, 96, 96, 0);
  rp(e1_wc, wcE1, 64, 96, 96, 0);
  rp(d0_wg, wgD0, 128, 128, 128, 0);
  rp(d0_wc, wcD0, 64, 128, 128, 0);
  rp(d1_wg, wgD1, 64, 96, 96, 0);
  rp(d1_wc, wcD1, 32, 96, 96, 0);
  hipLaunchKernelGGL(xcvt, dim3(200), dim3(1024), 0, stream, x, xf,
                     B_ * T_ * F_ / 4);

  hipFuncSetAttribute((const void*)ae_kernel,
                      hipFuncAttributeMaxDynamicSharedMemorySize, LDS_TOTAL);
  hipLaunchKernelGGL(ae_kernel, dim3(B_), dim3(512), LDS_TOTAL, stream, xf, out,
                     wgE0, wcE0, e0_bg, e0_bc, wgE1, wcE1, e1_bg, e1_bc,
                     wgD0, wcD0, d0_bg, d0_bc, wgD1, wcD1, d1_bg, d1_bc,
                     fw, fb, y1g);
}

// Round 9
// 1247.467 us; speedup vs baseline: 1.2553x; 1.2553x over previous
//
#include <hip/hip_runtime.h>
#include <cstdint>
#include <cstddef>

// ConvGRU autoencoder, round 9: r7 structure + REAL register-resident weights.
// Key fix vs r7/r8: __launch_bounds__(512,1) lifts the VGPR cap to 256 (LDS
// already forces 1 block/CU; 2 waves/SIMD unchanged). e1 gates+cand and d0
// gates are now truly VGPR-resident (enc/dec liveness disjoint) -- kills the
// phantom per-timestep global weight reloads that r7/r8 suffered (VGPR=120/128
// proved the compiler was rematerializing "register" weights from HBM/L2 every
// t). e0/d1 weights + d0 cand stay in LDS.
//
// aT layout (28 cb x 130 rows x 8 f16) @ byte 104448, identical to r7:
//  enc: cb0 x, cb1-4 h0, cb5-12 h1, cb13 x-dup, cb14-17 rh0, cb18-25 rh1
//  dec: cb0-7 y1, cb8-15 hd0, cb16-19 hd1, cb20-27 rh
// Weights LDS: enc wgE0@0 wcE0@24576; dec wcD0@0 wgD1@49152 wcD1@86016.

#define F_ 128
#define T_ 100
#define B_ 64
#define ROWSP 130
#define CBSTR (ROWSP * 8)    // f16 per cb
#define CBBYTE (ROWSP * 16)  // bytes per cb
#define AT_OFF 104448
#define LDS_TOTAL (AT_OFF + 28 * CBBYTE)  // 162688

typedef _Float16 f16;
typedef __attribute__((ext_vector_type(4))) float f32x4;
typedef __attribute__((ext_vector_type(8))) _Float16 f16x8;
typedef __attribute__((ext_vector_type(4))) _Float16 f16x4;

#define MFMA(a, b, c) __builtin_amdgcn_mfma_f32_16x16x32_f16(a, b, c, 0, 0, 0)

__device__ __forceinline__ float exp2_(float x) { return __builtin_amdgcn_exp2f(x); }
__device__ __forceinline__ float rcp_(float x) { return __builtin_amdgcn_rcpf(x); }

#define KSG (-1.442695041f)  // sigmoid: sig(v) = rcp(1+exp2(v*KSG))
#define KTH (-2.885390082f)  // tanh:    tanh(v) = 2*rcp(1+exp2(v*KTH)) - 1

// cb base per (layer, ks%NC3); fragment cb = base + kb (kb = lane>>4).
__host__ __device__ constexpr int cbA(int lid, int km) {
  return lid == 0 ? (km ? 4 : 0)
       : lid == 1 ? (1 + km * 4)
       : lid == 2 ? (km * 4)
                  : (8 + km * 4);
}
__host__ __device__ constexpr int cbB(int lid, int km) {
  return lid == 0 ? (km ? 17 : 13)
       : lid == 1 ? (km == 0 ? 1 : 14 + km * 4)
       : lid == 2 ? (km < 2 ? km * 4 : 12 + km * 4)
                  : (km < 2 ? 8 + km * 4 : 20);
}

// One GRU layer step (r7 structure). Gate weights: regs (GREG) or LDS; cand
// weights: regs (CREG) or LDS. One internal barrier (after rh write).
// Caller barriers before (inputs ready) and after (h visible).
template <int LID, int NCR, int NK, int NC3, int HC, int RHC,
          bool GREG, bool CREG, bool EMITY1>
__device__ __forceinline__ void gru_layer(
    const f16* __restrict__ rdB, char* __restrict__ wrB,
    const f16x8* __restrict__ aR, const f16x8* __restrict__ aU,
    const f16* __restrict__ gR, const f16* __restrict__ gU,
    const f16x8* __restrict__ cR, const f16* __restrict__ cW,
    const f32x4 bR2, const f32x4 bU2, const f32x4 bC2,
    f32x4* __restrict__ hreg, f16* __restrict__ y1dst) {
  constexpr int FTW = NCR;
  // ---- conv A: R,U gates over [x ; h] ----
  f32x4 accR[FTW], accU[FTW];
#pragma unroll
  for (int j = 0; j < FTW; ++j) {
    accR[j] = (f32x4){0.f, 0.f, 0.f, 0.f};
    accU[j] = (f32x4){0.f, 0.f, 0.f, 0.f};
  }
#pragma unroll
  for (int ks = 0; ks < NK; ++ks) {
    const int k = ks / NC3, km = ks % NC3;
    const f16* fb = rdB + cbA(LID, km) * CBSTR + k * 8;
    f16x8 bf[FTW];
#pragma unroll
    for (int j = 0; j < FTW; ++j) bf[j] = *(const f16x8*)(fb + j * 128);
    f16x8 wr, wu;
    if constexpr (GREG) {
      wr = aR[ks];
      wu = aU[ks];
    } else {
      wr = *(const f16x8*)(gR + ks * 512);
      wu = *(const f16x8*)(gU + ks * 512);
    }
#pragma unroll
    for (int j = 0; j < FTW; ++j) accR[j] = MFMA(wr, bf[j], accR[j]);
#pragma unroll
    for (int j = 0; j < FTW; ++j) accU[j] = MFMA(wu, bf[j], accU[j]);
  }
  // ---- post A: rh = sigm(R)*h into rh cols (u deferred to post B) ----
#pragma unroll
  for (int j = 0; j < FTW; ++j) {
    f16x4 rh;
#pragma unroll
    for (int q = 0; q < 4; ++q) {
      const float r = rcp_(1.0f + exp2_(fmaf(accR[j][q], KSG, bR2[q])));
      rh[q] = (f16)(r * hreg[j][q]);
    }
    *(f16x4*)(wrB + (RHC >> 3) * CBBYTE + j * 256) = rh;
  }
  __syncthreads();  // rh visible to all waves
  // ---- conv B: candidate over [x ; r*h] ----
  f32x4 accC[FTW];
#pragma unroll
  for (int j = 0; j < FTW; ++j) accC[j] = (f32x4){0.f, 0.f, 0.f, 0.f};
#pragma unroll
  for (int ks = 0; ks < NK; ++ks) {
    const int k = ks / NC3, km = ks % NC3;
    const f16* fb = rdB + cbB(LID, km) * CBSTR + k * 8;
    f16x8 bf[FTW];
#pragma unroll
    for (int j = 0; j < FTW; ++j) bf[j] = *(const f16x8*)(fb + j * 128);
    f16x8 wc;
    if constexpr (CREG) wc = cR[ks];
    else wc = *(const f16x8*)(cW + ks * 512);
#pragma unroll
    for (int j = 0; j < FTW; ++j) accC[j] = MFMA(wc, bf[j], accC[j]);
  }
  // ---- post B: u = sigm(U); h = h + u*(tanh(C) - h); write h cols ----
#pragma unroll
  for (int j = 0; j < FTW; ++j) {
    f16x4 hh;
#pragma unroll
    for (int q = 0; q < 4; ++q) {
      const float u = rcp_(1.0f + exp2_(fmaf(accU[j][q], KSG, bU2[q])));
      const float r = rcp_(1.0f + exp2_(fmaf(accC[j][q], KTH, bC2[q])));
      const float h = hreg[j][q];
      const float s = fmaf(2.0f, r, -(1.0f + h));  // tanh(C) - h
      const float hn = fmaf(u, s, h);
      hreg[j][q] = hn;
      hh[q] = (f16)hn;
    }
    *(f16x4*)(wrB + (HC >> 3) * CBBYTE + j * 256) = hh;
    if constexpr (EMITY1) *(f16x4*)(y1dst + j * 128) = hh;
  }
}

__global__ __launch_bounds__(512, 1) void ae_kernel(
    const f16* __restrict__ xf, float* __restrict__ out,
    const f16* __restrict__ wgE0, const f16* __restrict__ wcE0,
    const float* __restrict__ bgE0, const float* __restrict__ bcE0,
    const f16* __restrict__ wgE1, const f16* __restrict__ wcE1,
    const float* __restrict__ bgE1, const float* __restrict__ bcE1,
    const f16* __restrict__ wgD0, const f16* __restrict__ wcD0,
    const float* __restrict__ bgD0, const float* __restrict__ bcD0,
    const f16* __restrict__ wgD1, const f16* __restrict__ wcD1,
    const float* __restrict__ bgD1, const float* __restrict__ bcD1,
    const float* __restrict__ fw, const float* __restrict__ fb,
    f16* __restrict__ y1g) {
  extern __shared__ char smem[];
  f16* aT = (f16*)(smem + AT_OFF);
  const int tid = threadIdx.x, b = blockIdx.x;
  const int w = tid >> 6, l = tid & 63;
  const int m16 = l & 15, kb = l >> 4;

  // zero aT (28 cb)
  for (int i = tid; i < 28 * CBBYTE / 16; i += 512)
    ((f32x4*)(smem + AT_OFF))[i] = (f32x4){0.f, 0.f, 0.f, 0.f};
  // encoder LDS weights: wgE0@0 (24576 B), wcE0@24576 (12288 B)
  for (int i = tid; i < 1536; i += 512)
    ((f16x8*)(smem + 0))[i] = ((const f16x8*)wgE0)[i];
  for (int i = tid; i < 768; i += 512)
    ((f16x8*)(smem + 24576))[i] = ((const f16x8*)wcE0)[i];

  // e1 gate + cand weights -> VGPRs (truly resident: 256-reg budget)
  const int cot2 = w & 1, cot4 = w & 3;
  f16x8 aR1[9], aU1[9], cE1[9];
#pragma unroll
  for (int ks = 0; ks < 9; ++ks) {
    aR1[ks] = ((const f16x8*)wgE1)[(cot4 * 9 + ks) * 64 + l];
    aU1[ks] = ((const f16x8*)wgE1)[((cot4 + 4) * 9 + ks) * 64 + l];
    cE1[ks] = ((const f16x8*)wcE1)[(cot4 * 9 + ks) * 64 + l];
  }
  // enc biases (scale folded)
  const int co2 = cot2 * 16 + kb * 4;
  const int co4 = cot4 * 16 + kb * 4;
  f32x4 bRe0, bUe0, bCe0, bRe1, bUe1, bCe1;
#pragma unroll
  for (int q = 0; q < 4; ++q) {
    bRe0[q] = bgE0[co2 + q] * KSG;
    bUe0[q] = bgE0[32 + co2 + q] * KSG;
    bCe0[q] = bcE0[co2 + q] * KTH;
    bRe1[q] = bgE1[co4 + q] * KSG;
    bUe1[q] = bgE1[64 + co4 + q] * KSG;
    bCe1[q] = bcE1[co4 + q] * KTH;
  }
  // per-thread LDS bases (2-tile and 4-tile variants)
  const int ft2 = (w >> 1) * 2, ft4 = (w >> 2) * 4;
  const f16* rdB2 = aT + kb * CBSTR + (ft2 * 16 + m16) * 8;
  const f16* rdB4 = aT + kb * CBSTR + (ft4 * 16 + m16) * 8;
  char* wrB2 = (char*)aT + (cot2 * 2 + (kb >> 1)) * CBBYTE +
               (ft2 * 16 + m16 + 1) * 16 + (kb & 1) * 8;
  char* wrB4 = (char*)aT + (cot4 * 2 + (kb >> 1)) * CBBYTE +
               (ft4 * 16 + m16 + 1) * 16 + (kb & 1) * 8;
  f16* y1t = y1g + (size_t)b * T_ * 8192 +
             ((cot4 * 2 + (kb >> 1)) * 128 + ft4 * 16 + m16) * 8 + (kb & 1) * 4;
  // LDS weight pointers
  const f16* gE0R = (const f16*)(smem + 0) + (cot2 * 6) * 512 + l * 8;
  const f16* gE0U = (const f16*)(smem + 0) + ((2 + cot2) * 6) * 512 + l * 8;
  const f16* cE0 = (const f16*)(smem + 24576) + (cot2 * 6) * 512 + l * 8;

  f32x4 h0r[2], h1r[4];
#pragma unroll
  for (int j = 0; j < 2; ++j) h0r[j] = (f32x4){0.f, 0.f, 0.f, 0.f};
#pragma unroll
  for (int j = 0; j < 4; ++j) h1r[j] = (f32x4){0.f, 0.f, 0.f, 0.f};
  __syncthreads();

  // ================= encoder =================
  const f16* xb = xf + (size_t)b * T_ * F_;
  for (int t = 0; t < T_; ++t) {
    if (tid < F_) {  // x into col 0 (cb0) and dup col 104 (cb13)
      const f16 v = xb[t * F_ + tid];
      aT[(tid + 1) * 8] = v;
      aT[13 * CBSTR + (tid + 1) * 8] = v;
    }
    __syncthreads();
    gru_layer<0, 2, 6, 2, 8, 112, false, false, false>(
        rdB2, wrB2, nullptr, nullptr, gE0R, gE0U, nullptr, cE0,
        bRe0, bUe0, bCe0, h0r, nullptr);
    __syncthreads();
    gru_layer<1, 4, 9, 3, 40, 144, true, true, true>(
        rdB4, wrB4, aR1, aU1, nullptr, nullptr, cE1, nullptr,
        bRe1, bUe1, bCe1, h1r, y1t + t * 8192);
    __syncthreads();
  }

  // ================= switch to decoder =================
  {  // hd0 init cols 64+ (from h1r, e1 tiling); hd1 init cols 128+ (h0r)
#pragma unroll
    for (int j = 0; j < 4; ++j) {
      f16x4 hh;
#pragma unroll
      for (int q = 0; q < 4; ++q) hh[q] = (f16)h1r[j][q];
      *(f16x4*)(wrB4 + 8 * CBBYTE + j * 256) = hh;
    }
#pragma unroll
    for (int j = 0; j < 2; ++j) {
      f16x4 hh;
#pragma unroll
      for (int q = 0; q < 4; ++q) hh[q] = (f16)h0r[j][q];
      *(f16x4*)(wrB2 + 16 * CBBYTE + j * 256) = hh;
    }
  }
  // decoder LDS weights: wcD0@0 (49152 B), wgD1@49152 (36864 B),
  // wcD1@86016 (18432 B). Enc weight reads all done at loop-end barrier.
  for (int i = tid; i < 3072; i += 512)
    ((f16x8*)(smem + 0))[i] = ((const f16x8*)wcD0)[i];
  for (int i = tid; i < 2304; i += 512)
    ((f16x8*)(smem + 49152))[i] = ((const f16x8*)wgD1)[i];
  for (int i = tid; i < 1152; i += 512)
    ((f16x8*)(smem + 86016))[i] = ((const f16x8*)wcD1)[i];
  // d0 gate weights -> VGPRs (enc regs dead; regalloc reuses)
  f16x8 aR0[12], aU0[12];
#pragma unroll
  for (int ks = 0; ks < 12; ++ks) {
    aR0[ks] = ((const f16x8*)wgD0)[(cot4 * 12 + ks) * 64 + l];
    aU0[ks] = ((const f16x8*)wgD0)[((cot4 + 4) * 12 + ks) * 64 + l];
  }
  // dec biases
  f32x4 bRd0, bUd0, bCd0, bRd1, bUd1, bCd1;
#pragma unroll
  for (int q = 0; q < 4; ++q) {
    bRd0[q] = bgD0[co4 + q] * KSG;
    bUd0[q] = bgD0[64 + co4 + q] * KSG;
    bCd0[q] = bcD0[co4 + q] * KTH;
    bRd1[q] = bgD1[co2 + q] * KSG;
    bUd1[q] = bgD1[32 + co2 + q] * KSG;
    bCd1[q] = bcD1[co2 + q] * KTH;
  }
  const f16* cD0 = (const f16*)(smem + 0) + (cot4 * 12) * 512 + l * 8;
  const f16* gD1R = (const f16*)(smem + 49152) + (cot2 * 9) * 512 + l * 8;
  const f16* gD1U = (const f16*)(smem + 49152) + ((2 + cot2) * 9) * 512 + l * 8;
  const f16* cD1 = (const f16*)(smem + 86016) + (cot2 * 9) * 512 + l * 8;
  __syncthreads();

  // ================= decoder =================
  for (int t = 0; t < T_; ++t) {
    {  // ingest y1(t) -> cb0-7
      const f16x8* src = (const f16x8*)(y1g + ((size_t)b * T_ + t) * 8192);
#pragma unroll
      for (int k2 = 0; k2 < 2; ++k2) {
        const int i = tid + k2 * 512;
        *(f16x8*)&aT[(i >> 7) * CBSTR + ((i & 127) + 1) * 8] = src[i];
      }
    }
    __syncthreads();
    gru_layer<2, 4, 12, 4, 64, 160, true, false, false>(
        rdB4, wrB4, aR0, aU0, nullptr, nullptr, nullptr, cD0,
        bRd0, bUd0, bCd0, h1r, nullptr);
    __syncthreads();
    gru_layer<3, 2, 9, 3, 128, 160, false, false, false>(
        rdB2, wrB2, nullptr, nullptr, gD1R, gD1U, nullptr, cD1,
        bRd1, bUd1, bCd1, h0r, nullptr);
    __syncthreads();
    if (tid < F_) {  // final 1x1 conv over hd1 (cb16-19)
      float s = fb[0];
#pragma unroll
      for (int cb = 0; cb < 4; ++cb) {
        const f16x8 h8 = *(const f16x8*)&aT[(16 + cb) * CBSTR + (tid + 1) * 8];
#pragma unroll
        for (int q = 0; q < 8; ++q) s = fmaf(fw[cb * 8 + q], (float)h8[q], s);
      }
      out[((size_t)b * T_ + t) * F_ + tid] = s;
    }
  }
}

// (CO,CI,3,3) fp32 -> f16 packed per MFMA A-fragment:
// dst[((cot*NK+ks)*64+lane)*8+j] = W[cot*16+(lane&15)][kk=ks*32+(lane>>4)*8+j]
__global__ void repack_f16(const float* __restrict__ src, f16* __restrict__ dst,
                           int CO, int CI, int CINH, int NK, int e0map) {
  const int n = (CO / 16) * NK * 64;
  for (int i = blockIdx.x * blockDim.x + threadIdx.x; i < n;
       i += gridDim.x * blockDim.x) {
    const int cot = i / (NK * 64);
    const int r = i - cot * NK * 64;
    const int ks = r >> 6, lph = r & 63;
    const int co = cot * 16 + (lph & 15);
    const int kbl = lph >> 4;
#pragma unroll
    for (int j = 0; j < 8; ++j) {
      const int kk = ks * 32 + kbl * 8 + j;
      const int k = kk / CINH, c = kk - k * CINH;
      int ci;
      if (e0map) ci = (c == 0) ? 0 : ((c >= 8 && c < 40) ? c - 7 : -1);
      else ci = (c < CI) ? c : -1;
      float wv = 0.f;
      if (ci >= 0) wv = src[((size_t)(co * CI + ci) * 3 + k) * 3 + 1];
      dst[(size_t)i * 8 + j] = (f16)wv;
    }
  }
}

__global__ void xcvt(const float* __restrict__ x, f16* __restrict__ xf, int n4) {
  for (int i = blockIdx.x * blockDim.x + threadIdx.x; i < n4;
       i += gridDim.x * blockDim.x) {
    const float4 v = ((const float4*)x)[i];
    f16x4 o;
    o[0] = (f16)v.x; o[1] = (f16)v.y; o[2] = (f16)v.z; o[3] = (f16)v.w;
    ((f16x4*)xf)[i] = o;
  }
}

extern "C" void kernel_launch(void* const* d_in, const int* in_sizes, int n_in,
                              void* d_out, int out_size, void* d_ws, size_t ws_size,
                              hipStream_t stream) {
  (void)in_sizes; (void)n_in; (void)out_size; (void)ws_size;
  const float* x = (const float*)d_in[0];
  const float* e0_wg = (const float*)d_in[1];
  const float* e0_bg = (const float*)d_in[2];
  const float* e0_wc = (const float*)d_in[3];
  const float* e0_bc = (const float*)d_in[4];
  const float* e1_wg = (const float*)d_in[5];
  const float* e1_bg = (const float*)d_in[6];
  const float* e1_wc = (const float*)d_in[7];
  const float* e1_bc = (const float*)d_in[8];
  const float* d0_wg = (const float*)d_in[9];
  const float* d0_bg = (const float*)d_in[10];
  const float* d0_wc = (const float*)d_in[11];
  const float* d0_bc = (const float*)d_in[12];
  const float* d1_wg = (const float*)d_in[13];
  const float* d1_bg = (const float*)d_in[14];
  const float* d1_wc = (const float*)d_in[15];
  const float* d1_bc = (const float*)d_in[16];
  const float* fw = (const float*)d_in[17];
  const float* fb = (const float*)d_in[18];
  float* out = (float*)d_out;

  char* p = (char*)d_ws;
  f16* y1g = (f16*)p;
  p += (size_t)B_ * T_ * 64 * 128 * 2;  // 104.86 MB
  f16* xf = (f16*)p;
  p += (size_t)B_ * T_ * F_ * 2;        // 1.64 MB
  auto aw = [&](int n) { f16* q = (f16*)p; p += (size_t)n * 2; return q; };
  f16* wgE0 = aw(64 * 192);
  f16* wcE0 = aw(32 * 192);
  f16* wgE1 = aw(128 * 288);
  f16* wcE1 = aw(64 * 288);
  f16* wgD0 = aw(128 * 384);
  f16* wcD0 = aw(64 * 384);
  f16* wgD1 = aw(64 * 288);
  f16* wcD1 = aw(32 * 288);

  auto rp = [&](const float* s, f16* d, int CO, int CI, int CINH, int e0m) {
    const int NK = 3 * CINH / 32;
    const int n = (CO / 16) * NK * 64;
    hipLaunchKernelGGL(repack_f16, dim3((n + 255) / 256), dim3(256), 0, stream,
                       s, d, CO, CI, CINH, NK, e0m);
  };
  rp(e0_wg, wgE0, 64, 33, 64, 1);
  rp(e0_wc, wcE0, 32, 33, 64, 1);
  rp(e1_wg, wgE1, 128, 96, 96, 0);
  rp(e1_wc, wcE1, 64, 96, 96, 0);
  rp(d0_wg, wgD0, 128, 128, 128, 0);
  rp(d0_wc, wcD0, 64, 128, 128, 0);
  rp(d1_wg, wgD1, 64, 96, 96, 0);
  rp(d1_wc, wcD1, 32, 96, 96, 0);
  hipLaunchKernelGGL(xcvt, dim3(200), dim3(1024), 0, stream, x, xf,
                     B_ * T_ * F_ / 4);

  hipFuncSetAttribute((const void*)ae_kernel,
                      hipFuncAttributeMaxDynamicSharedMemorySize, LDS_TOTAL);
  hipLaunchKernelGGL(ae_kernel, dim3(B_), dim3(512), LDS_TOTAL, stream, xf, out,
                     wgE0, wcE0, e0_bg, e0_bc, wgE1, wcE1, e1_bg, e1_bc,
                     wgD0, wcD0, d0_bg, d0_bc, wgD1, wcD1, d1_bg, d1_bc,
                     fw, fb, y1g);
}